// Round 7
// baseline (66.562 us; speedup 1.0000x reference)
//
#include <hip/hip_runtime.h>
#include <math.h>

#define CH 40
#define IMW 1024
#define XS 48                 // halves per x1 position (padded from 40; 40..47 never read)
#define W2T_HALVES (48*48*8)  // [kchunk 0..47][co 0..47][j 0..7] = 18432 halves = 36864 B
#define Z1_OFF W2T_HALVES     // z1[40] halves right after w2t
#define Y2S 50                // f32 stride of y2 transpose buffer

typedef _Float16 v8h __attribute__((ext_vector_type(8)));
typedef _Float16 v2h __attribute__((ext_vector_type(2)));
typedef float    v4f __attribute__((ext_vector_type(4)));
typedef float    v2f __attribute__((ext_vector_type(2)));

// gelu(tanh approx) == x * sigmoid(2*0.79788456*(x+0.044715x^3))
__device__ __forceinline__ float gelu_fast(float x) {
    float u = 1.5957691216057308f * (x + 0.044715f * x * x * x);
    return x * __builtin_amdgcn_rcpf(1.0f + __expf(-u));
}

// ---------------- pre-kernel: build f16 weight table + z1 in ws ----------------
__global__ __launch_bounds__(256) void prep_kernel(
    const float* __restrict__ w2,
    const float* __restrict__ b1, const float* __restrict__ s1,
    const float* __restrict__ bb1,
    _Float16* __restrict__ ws)
{
    int idx0 = blockIdx.x * 256 + threadIdx.x;
    for (int idx = idx0; idx < W2T_HALVES; idx += gridDim.x * 256) {
        int j   = idx & 7;
        int co  = (idx >> 3) % 48;
        int kgg = idx / (48 * 8);
        int k   = kgg * 8 + j;          // k = window*40 + ci
        float v = 0.0f;
        if (co < CH && k < 360) {
            int wi = k / 40, ci = k - wi * 40;
            v = w2[(wi * CH + ci) * CH + co];
        }
        ws[idx] = (_Float16)v;
    }
    if (blockIdx.x == 0 && threadIdx.x < CH) {
        int t = threadIdx.x;
        float mu = 0.f, m2 = 0.f;
        for (int i = 0; i < CH; i++) mu += b1[i];
        mu /= CH;
        for (int i = 0; i < CH; i++) { float d = b1[i] - mu; m2 += d * d; }
        float rs = rsqrtf(m2 / CH + 1e-6f);
        float y = (b1[t] - mu) * rs * s1[t] + bb1[t];
        ws[Z1_OFF + t] = (_Float16)gelu_fast(y);
    }
}

// ---------------- main kernel: one token per block ----------------
__global__ __launch_bounds__(256) void sgn_kernel(
    const float* __restrict__ img,
    const float* __restrict__ w1, const float* __restrict__ b1,
    const float* __restrict__ s1, const float* __restrict__ bb1,
    const float* __restrict__ b2g,
    const float* __restrict__ s2, const float* __restrict__ bb2,
    const float* __restrict__ dw, const float* __restrict__ db,
    const _Float16* __restrict__ ws,
    float* __restrict__ out)
{
    // x1h f16 [17*17*XS] = 27744 B; after conv2 reads, overlaid by y2 f32 [64][Y2S] = 12800 B
    __shared__ __align__(16) unsigned char sbuf[17 * 17 * XS * 2];
    _Float16* x1h = (_Float16*)sbuf;
    float*    y2  = (float*)sbuf;
    __shared__ __align__(16) _Float16 w2t_lds[W2T_HALVES];  // 36864 B, staged from ws
    __shared__ float img_s[16][16];
    __shared__ float w1t[40 * 12];     // conv1 weights transposed [ch][k], k padded to 12
    __shared__ float p1s[120];         // b1 | s1 | bb1
    __shared__ float p2s[120];         // b2 | s2 | bb2
    __shared__ unsigned koff_s[48];
    __shared__ float red[4][6];

    const int f   = blockIdx.x;
    const int cfg = f >> 10;
    const int ij  = f & 1023;
    const int ti  = ij >> 5, tj = ij & 31;
    const int sx  = cfg & 1, sy = cfg >> 1;
    const int cr  = 2 * ti + sx, cc = 2 * tj + sy;

    const int t = threadIdx.x;

    // ---- Phase A: stage image cell, params, w1 transpose, koff LUT ----
    {
        int r = t >> 4, c = t & 15;
        img_s[r][c] = img[(cr * 16 + r) * IMW + cc * 16 + c];
    }
    for (int i = t; i < 360; i += 256) {
        int k = i / 40, ch = i - k * 40;
        w1t[ch * 12 + k] = w1[i];
    }
    if (t < 120) {
        p1s[t] = (t < 40) ? b1[t] : (t < 80 ? s1[t - 40] : bb1[t - 80]);
    } else if (t >= 128 && t < 248) {
        int i = t - 128;
        p2s[i] = (i < 40) ? b2g[i] : (i < 80 ? s2[i - 40] : bb2[i - 80]);
    }
    if (t < 48) {
        int s = t >> 2, kg = t & 3;
        int k0 = 32 * s + 8 * kg;
        unsigned v;
        if (k0 >= 360) v = 0x80000000u;
        else {
            int wi = k0 / 40, ci0 = k0 - wi * 40;
            int dr = wi / 3, dc = wi - 3 * dr;
            v = (unsigned)((dr * 17 + dc) * XS + ci0);
        }
        koff_s[t] = v;
    }
    __syncthreads();

    // ---- w2t staging, part 1: issue global loads EARLY (latency hides under conv1) ----
    v8h wreg[9];
    #pragma unroll
    for (int r = 0; r < 9; r++)
        wreg[r] = *(const v8h*)&ws[(r * 256 + t) * 8];

    // ---- Phase B: conv1 + LN1 + gelu -> x1h (f16); 4 threads/pos, 10 ch each ----
    {
        const int pos = t >> 2, sub = t & 3;
        const int r = pos >> 3, c = pos & 7;
        float vin[9];
        #pragma unroll
        for (int dr = 0; dr < 3; dr++)
            #pragma unroll
            for (int dc = 0; dc < 3; dc++) {
                int rr = 2 * r + dr, ccc = 2 * c + dc;
                vin[dr * 3 + dc] = (rr < 16 && ccc < 16) ? img_s[rr][ccc] : 0.0f;
            }
        const int ch0 = sub * 10;
        float y[10];
        float s_own = 0.f;
        #pragma unroll
        for (int u = 0; u < 10; u++) {
            float a = p1s[ch0 + u];
            const float* wr = &w1t[(ch0 + u) * 12];
            #pragma unroll
            for (int k = 0; k < 9; k++) a += vin[k] * wr[k];
            y[u] = a; s_own += a;
        }
        s_own += __shfl_xor(s_own, 1, 64);
        s_own += __shfl_xor(s_own, 2, 64);
        float mu = s_own * (1.0f / CH);
        float v_own = 0.f;
        #pragma unroll
        for (int u = 0; u < 10; u++) { float d = y[u] - mu; v_own += d * d; }
        v_own += __shfl_xor(v_own, 1, 64);
        v_own += __shfl_xor(v_own, 2, 64);
        float rs = rsqrtf(v_own * (1.0f / CH) + 1e-6f);
        const int base = (r * 17 + c) * XS + ch0;   // halves, byte addr 4-aligned
        #pragma unroll
        for (int u2 = 0; u2 < 5; u2++) {
            v2h hv;
            int ch_a = ch0 + 2 * u2, ch_b = ch_a + 1;
            hv[0] = (_Float16)gelu_fast((y[2*u2]   - mu) * rs * p1s[40 + ch_a] + p1s[80 + ch_a]);
            hv[1] = (_Float16)gelu_fast((y[2*u2+1] - mu) * rs * p1s[40 + ch_b] + p1s[80 + ch_b]);
            *(v2h*)&x1h[base + 2 * u2] = hv;
        }
    }
    // border/constant fill: 225 non-real positions across 256 threads (2 rounds)
    {
        const v8h* zsrc = (const v8h*)&ws[Z1_OFF];
        v8h z0 = zsrc[0], z1v = zsrc[1], z2 = zsrc[2], z3 = zsrc[3], z4 = zsrc[4];
        v8h zz = (v8h)0;
        #pragma unroll
        for (int round = 0; round < 2; round++) {
            int pp = t + round * 256;
            if (pp >= 289) continue;
            int r = pp / 17, c = pp - r * 17;
            if (r < 8 && c < 8) continue;
            bool zero = (r == 16) || (c == 16);
            int base = pp * XS;
            *(v8h*)&x1h[base]      = zero ? zz : z0;
            *(v8h*)&x1h[base + 8]  = zero ? zz : z1v;
            *(v8h*)&x1h[base + 16] = zero ? zz : z2;
            *(v8h*)&x1h[base + 24] = zero ? zz : z3;
            *(v8h*)&x1h[base + 32] = zero ? zz : z4;
        }
    }
    // ---- w2t staging, part 2: write arrived data to LDS ----
    #pragma unroll
    for (int r = 0; r < 9; r++)
        *(v8h*)&w2t_lds[(r * 256 + t) * 8] = wreg[r];
    __syncthreads();

    // ---- Phase C: conv2 MFMA GEMM; wave wv owns M-tile wv (16 pos), full K, N=48 ----
    // B-fragments now from LDS (w2t_lds) instead of L2.
    v4f acc0 = {0,0,0,0}, acc1 = {0,0,0,0}, acc2 = {0,0,0,0};
    {
        const int wv   = t >> 6;
        const int lane = t & 63;
        const int row  = lane & 15;
        const int kg   = lane >> 4;
        const int o    = (wv << 4) | row;
        const int p = o >> 3, q = o & 7;
        const unsigned pbase = (unsigned)((34 * p + 2 * q) * XS);

        #pragma unroll
        for (int s = 0; s < 12; s++) {
            unsigned koff = koff_s[(s << 2) | kg];
            unsigned aoff = (koff & 0x80000000u) ? 0u : (pbase + koff);
            v8h a = *(const v8h*)&x1h[aoff];
            const _Float16* wb = &w2t_lds[(((s * 4 + kg) * 48) + row) * 8];
            v8h bf0 = *(const v8h*)&wb[0];
            v8h bf1 = *(const v8h*)&wb[16 * 8];
            v8h bf2 = *(const v8h*)&wb[32 * 8];
            acc0 = __builtin_amdgcn_mfma_f32_16x16x32_f16(a, bf0, acc0, 0, 0, 0);
            acc1 = __builtin_amdgcn_mfma_f32_16x16x32_f16(a, bf1, acc1, 0, 0, 0);
            acc2 = __builtin_amdgcn_mfma_f32_16x16x32_f16(a, bf2, acc2, 0, 0, 0);
        }
    }
    __syncthreads();   // all x1h reads complete; safe to overwrite with y2

    // ---- transpose raw conv2 output to y2 [64][Y2S] ----
    {
        const int wv   = t >> 6;
        const int lane = t & 63;
        const int co_b = lane & 15;
        const int kg   = lane >> 4;
        #pragma unroll
        for (int j = 0; j < 4; j++) {
            int pos = (wv << 4) | (kg << 2) | j;
            y2[pos * Y2S + co_b]      = acc0[j];
            y2[pos * Y2S + 16 + co_b] = acc1[j];
            if (co_b < 8)
                y2[pos * Y2S + 32 + co_b] = acc2[j];
        }
    }
    __syncthreads();

    // ---- Phase D: bias + LN2 + gelu + dense; 4 threads/pos, 10 ch each ----
    {
        const int pos = t >> 2, sub = t & 3;
        const int co0 = sub * 10;
        float vv[10];
        float s_own = 0.f;
        #pragma unroll
        for (int u2 = 0; u2 < 5; u2++) {
            v2f x = *(const v2f*)&y2[pos * Y2S + co0 + 2 * u2];
            float a = x[0] + p2s[co0 + 2 * u2];
            float b = x[1] + p2s[co0 + 2 * u2 + 1];
            vv[2*u2] = a; vv[2*u2+1] = b;
            s_own += a + b;
        }
        s_own += __shfl_xor(s_own, 1, 64);
        s_own += __shfl_xor(s_own, 2, 64);
        float mu = s_own * (1.0f / CH);
        float v_own = 0.f;
        #pragma unroll
        for (int u = 0; u < 10; u++) { float d = vv[u] - mu; v_own += d * d; }
        v_own += __shfl_xor(v_own, 1, 64);
        v_own += __shfl_xor(v_own, 2, 64);
        float rs = rsqrtf(v_own * (1.0f / CH) + 1e-6f);

        float acc6[6] = {0.f, 0.f, 0.f, 0.f, 0.f, 0.f};
        const float* wp = &dw[(pos * CH + co0) * 6];
        #pragma unroll
        for (int u = 0; u < 10; u++) {
            float gv = gelu_fast((vv[u] - mu) * rs * p2s[40 + co0 + u] + p2s[80 + co0 + u]);
            v2f w01 = *(const v2f*)&wp[u * 6];
            v2f w23 = *(const v2f*)&wp[u * 6 + 2];
            v2f w45 = *(const v2f*)&wp[u * 6 + 4];
            acc6[0] += gv * w01[0]; acc6[1] += gv * w01[1];
            acc6[2] += gv * w23[0]; acc6[3] += gv * w23[1];
            acc6[4] += gv * w45[0]; acc6[5] += gv * w45[1];
        }
        #pragma unroll
        for (int off = 32; off > 0; off >>= 1)
            #pragma unroll
            for (int k = 0; k < 6; k++) acc6[k] += __shfl_down(acc6[k], off, 64);
        int wv = t >> 6, lane = t & 63;
        if (lane == 0) {
            #pragma unroll
            for (int k = 0; k < 6; k++) red[wv][k] = acc6[k];
        }
        __syncthreads();
        if (t == 0) {
            #pragma unroll
            for (int k = 0; k < 6; k++)
                out[f * 6 + k] = red[0][k] + red[1][k] + red[2][k] + red[3][k] + db[k];
        }
    }
}

extern "C" void kernel_launch(void* const* d_in, const int* in_sizes, int n_in,
                              void* d_out, int out_size, void* d_ws, size_t ws_size,
                              hipStream_t stream) {
    const float* img = (const float*)d_in[0];
    // d_in[1] = masks: analytically redundant (mask == cell id), not read.
    const float* w1  = (const float*)d_in[2];
    const float* b1  = (const float*)d_in[3];
    const float* s1  = (const float*)d_in[4];
    const float* bb1 = (const float*)d_in[5];
    const float* w2  = (const float*)d_in[6];
    const float* b2  = (const float*)d_in[7];
    const float* s2  = (const float*)d_in[8];
    const float* bb2 = (const float*)d_in[9];
    const float* dw  = (const float*)d_in[10];
    const float* db  = (const float*)d_in[11];
    float* out = (float*)d_out;
    _Float16* ws = (_Float16*)d_ws;

    prep_kernel<<<32, 256, 0, stream>>>(w2, b1, s1, bb1, ws);
    sgn_kernel<<<4096, 256, 0, stream>>>(img, w1, b1, s1, bb1,
                                         b2, s2, bb2, dw, db, ws, out);
}

// Round 8
// 50.510 us; speedup vs baseline: 1.3178x; 1.3178x over previous
//
#include <hip/hip_runtime.h>
#include <math.h>

#define CH 40
#define IMW 1024
#define TOKH (17*17*40)       // halves per token x1 tile = 11560 (23120 B, 16B-aligned)
#define W2T_HALVES (48*48*8)  // ws layout [kchunk 0..47][co 0..47][j 0..7]
#define Z1_OFF W2T_HALVES
#define Y2S 50                // f32 stride of y2 transpose buffer
#define Y2TOK (64*Y2S)        // floats per token y2

typedef _Float16 v8h __attribute__((ext_vector_type(8)));
typedef _Float16 v4h __attribute__((ext_vector_type(4)));
typedef float    v4f __attribute__((ext_vector_type(4)));
typedef float    v2f __attribute__((ext_vector_type(2)));

// gelu(tanh approx) == x * sigmoid(2*0.79788456*(x+0.044715x^3))
__device__ __forceinline__ float gelu_fast(float x) {
    float u = 1.5957691216057308f * (x + 0.044715f * x * x * x);
    return x * __builtin_amdgcn_rcpf(1.0f + __expf(-u));
}

// ---------------- pre-kernel: build f16 weight table + z1 in ws ----------------
__global__ __launch_bounds__(256) void prep_kernel(
    const float* __restrict__ w2,
    const float* __restrict__ b1, const float* __restrict__ s1,
    const float* __restrict__ bb1,
    _Float16* __restrict__ ws)
{
    int idx0 = blockIdx.x * 256 + threadIdx.x;
    for (int idx = idx0; idx < W2T_HALVES; idx += gridDim.x * 256) {
        int j   = idx & 7;
        int co  = (idx >> 3) % 48;
        int kgg = idx / (48 * 8);
        int k   = kgg * 8 + j;          // k = window*40 + ci
        float v = 0.0f;
        if (co < CH && k < 360) {
            int wi = k / 40, ci = k - wi * 40;
            v = w2[(wi * CH + ci) * CH + co];
        }
        ws[idx] = (_Float16)v;
    }
    if (blockIdx.x == 0 && threadIdx.x < CH) {
        int t = threadIdx.x;
        float mu = 0.f, m2 = 0.f;
        for (int i = 0; i < CH; i++) mu += b1[i];
        mu /= CH;
        for (int i = 0; i < CH; i++) { float d = b1[i] - mu; m2 += d * d; }
        float rs = rsqrtf(m2 / CH + 1e-6f);
        float y = (b1[t] - mu) * rs * s1[t] + bb1[t];
        ws[Z1_OFF + t] = (_Float16)gelu_fast(y);
    }
}

// ---------------- main kernel: TWO tokens per block ----------------
__global__ __launch_bounds__(256) void sgn_kernel(
    const float* __restrict__ img,
    const float* __restrict__ w1, const float* __restrict__ b1,
    const float* __restrict__ s1, const float* __restrict__ bb1,
    const float* __restrict__ b2g,
    const float* __restrict__ s2, const float* __restrict__ bb2,
    const float* __restrict__ dw, const float* __restrict__ db,
    const _Float16* __restrict__ ws,
    float* __restrict__ out)
{
    // x1h: 2 tokens x [17*17*40] f16 = 46240 B; later overlaid by y2: 2 x [64*Y2S] f32 = 25600 B
    __shared__ __align__(16) unsigned char sbuf[2 * TOKH * 2];
    _Float16* x1h = (_Float16*)sbuf;
    float*    y2  = (float*)sbuf;
    __shared__ float img_s[2][16][16];
    __shared__ float w1t[40 * 12];     // conv1 weights transposed [ch][k], k padded to 12
    __shared__ float p1s[120];         // b1 | s1 | bb1
    __shared__ float p2s[120];         // b2 | s2 | bb2
    __shared__ unsigned koff_s[48];
    __shared__ float red[4][2][6];

    const int t = threadIdx.x;

    // ---- token coords for the pair ----
    int crr[2], ccc2[2], fid[2];
    #pragma unroll
    for (int tk = 0; tk < 2; tk++) {
        int f   = blockIdx.x * 2 + tk;
        fid[tk] = f;
        int cfg = f >> 10;
        int ij  = f & 1023;
        int ti  = ij >> 5, tj = ij & 31;
        int sx  = cfg & 1, sy = cfg >> 1;
        crr[tk] = 2 * ti + sx;
        ccc2[tk] = 2 * tj + sy;
    }

    // ---- Phase A: stage 2 image cells, params, w1 transpose, koff LUT ----
    {
        int r = t >> 4, c = t & 15;
        #pragma unroll
        for (int tk = 0; tk < 2; tk++)
            img_s[tk][r][c] = img[(crr[tk] * 16 + r) * IMW + ccc2[tk] * 16 + c];
    }
    for (int i = t; i < 360; i += 256) {
        int k = i / 40, ch = i - k * 40;
        w1t[ch * 12 + k] = w1[i];
    }
    if (t < 120) {
        p1s[t] = (t < 40) ? b1[t] : (t < 80 ? s1[t - 40] : bb1[t - 80]);
    } else if (t >= 128 && t < 248) {
        int i = t - 128;
        p2s[i] = (i < 40) ? b2g[i] : (i < 80 ? s2[i - 40] : bb2[i - 80]);
    }
    if (t < 48) {
        int s = t >> 2, kg = t & 3;
        int k0 = 32 * s + 8 * kg;
        unsigned v;
        if (k0 >= 360) v = 0x80000000u;
        else {
            int wi = k0 / 40, ci0 = k0 - wi * 40;
            int dr = wi / 3, dc = wi - 3 * dr;
            v = (unsigned)((dr * 17 + dc) * 40 + ci0);
        }
        koff_s[t] = v;
    }
    __syncthreads();

    // ---- Phase B: conv1 + LN1 + gelu -> x1h; 2 threads/pos, 20 ch each; token = t>>7 ----
    {
        const int tk  = t >> 7;
        const int pos = (t >> 1) & 63;
        const int sub = t & 1;
        const int r = pos >> 3, c = pos & 7;
        float vin[9];
        #pragma unroll
        for (int dr = 0; dr < 3; dr++)
            #pragma unroll
            for (int dc = 0; dc < 3; dc++) {
                int rr = 2 * r + dr, cp = 2 * c + dc;
                vin[dr * 3 + dc] = (rr < 16 && cp < 16) ? img_s[tk][rr][cp] : 0.0f;
            }
        const int ch0 = sub * 20;
        float y[20];
        float s_own = 0.f;
        #pragma unroll
        for (int u = 0; u < 20; u++) {
            float a = p1s[ch0 + u];
            const float* wr = &w1t[(ch0 + u) * 12];
            #pragma unroll
            for (int k = 0; k < 9; k++) a += vin[k] * wr[k];
            y[u] = a; s_own += a;
        }
        s_own += __shfl_xor(s_own, 1, 64);
        float mu = s_own * (1.0f / CH);
        float v_own = 0.f;
        #pragma unroll
        for (int u = 0; u < 20; u++) { float d = y[u] - mu; v_own += d * d; }
        v_own += __shfl_xor(v_own, 1, 64);
        float rs = rsqrtf(v_own * (1.0f / CH) + 1e-6f);
        _Float16 g[20];
        #pragma unroll
        for (int u = 0; u < 20; u++) {
            int ch = ch0 + u;
            g[u] = (_Float16)gelu_fast((y[u] - mu) * rs * p1s[40 + ch] + p1s[80 + ch]);
        }
        const int base = tk * TOKH + (r * 17 + c) * 40 + ch0;
        if (sub == 0) {   // halves 0..19: 16B,16B,8B
            *(v8h*)&x1h[base]      = *(v8h*)&g[0];
            *(v8h*)&x1h[base + 8]  = *(v8h*)&g[8];
            *(v4h*)&x1h[base + 16] = *(v4h*)&g[16];
        } else {          // halves 20..39: 8B,16B,16B
            *(v4h*)&x1h[base]      = *(v4h*)&g[0];
            *(v8h*)&x1h[base + 4]  = *(v8h*)&g[4];
            *(v8h*)&x1h[base + 12] = *(v8h*)&g[12];
        }
    }
    // border/constant fill for both tokens (225 positions each)
    {
        const v8h* zsrc = (const v8h*)&ws[Z1_OFF];
        v8h z0 = zsrc[0], z1v = zsrc[1], z2 = zsrc[2], z3 = zsrc[3], z4 = zsrc[4];
        v8h zz = (v8h)0;
        #pragma unroll
        for (int tk = 0; tk < 2; tk++) {
            for (int pp = t; pp < 289; pp += 256) {
                int r = pp / 17, c = pp - r * 17;
                if (r < 8 && c < 8) continue;
                bool zero = (r == 16) || (c == 16);
                int base = tk * TOKH + pp * 40;
                *(v8h*)&x1h[base]      = zero ? zz : z0;
                *(v8h*)&x1h[base + 8]  = zero ? zz : z1v;
                *(v8h*)&x1h[base + 16] = zero ? zz : z2;
                *(v8h*)&x1h[base + 24] = zero ? zz : z3;
                *(v8h*)&x1h[base + 32] = zero ? zz : z4;
            }
        }
    }
    __syncthreads();

    // ---- Phase C: conv2 MFMA GEMM; B-fragments shared across both tokens ----
    v4f accA0 = {0,0,0,0}, accA1 = {0,0,0,0}, accA2 = {0,0,0,0};
    v4f accB0 = {0,0,0,0}, accB1 = {0,0,0,0}, accB2 = {0,0,0,0};
    {
        const int wv   = t >> 6;
        const int lane = t & 63;
        const int row  = lane & 15;
        const int kg   = lane >> 4;
        const int o    = (wv << 4) | row;
        const int p = o >> 3, q = o & 7;
        const unsigned pbase = (unsigned)((34 * p + 2 * q) * 40);

        #pragma unroll
        for (int s = 0; s < 12; s++) {
            const int kc = (s << 2) | kg;
            unsigned koff = koff_s[kc];
            unsigned aoff = (koff & 0x80000000u) ? 0u : (pbase + koff);
            v8h a0 = *(const v8h*)&x1h[aoff];
            v8h a1 = *(const v8h*)&x1h[TOKH + aoff];
            const _Float16* wb = &ws[(kc * 48 + row) * 8];
            v8h bf0 = *(const v8h*)&wb[0];
            v8h bf1 = *(const v8h*)&wb[16 * 8];
            v8h bf2 = *(const v8h*)&wb[32 * 8];
            accA0 = __builtin_amdgcn_mfma_f32_16x16x32_f16(a0, bf0, accA0, 0, 0, 0);
            accB0 = __builtin_amdgcn_mfma_f32_16x16x32_f16(a1, bf0, accB0, 0, 0, 0);
            accA1 = __builtin_amdgcn_mfma_f32_16x16x32_f16(a0, bf1, accA1, 0, 0, 0);
            accB1 = __builtin_amdgcn_mfma_f32_16x16x32_f16(a1, bf1, accB1, 0, 0, 0);
            accA2 = __builtin_amdgcn_mfma_f32_16x16x32_f16(a0, bf2, accA2, 0, 0, 0);
            accB2 = __builtin_amdgcn_mfma_f32_16x16x32_f16(a1, bf2, accB2, 0, 0, 0);
        }
    }
    __syncthreads();   // all x1h reads complete; safe to overwrite with y2

    // ---- transpose raw conv2 output to y2 [tk][64][Y2S] ----
    {
        const int wv   = t >> 6;
        const int lane = t & 63;
        const int co_b = lane & 15;
        const int kg   = lane >> 4;
        #pragma unroll
        for (int j = 0; j < 4; j++) {
            int pos = (wv << 4) | (kg << 2) | j;
            float* ya = &y2[pos * Y2S];
            float* yb = &y2[Y2TOK + pos * Y2S];
            ya[co_b]      = accA0[j];
            ya[16 + co_b] = accA1[j];
            yb[co_b]      = accB0[j];
            yb[16 + co_b] = accB1[j];
            if (co_b < 8) {
                ya[32 + co_b] = accA2[j];
                yb[32 + co_b] = accB2[j];
            }
        }
    }
    __syncthreads();

    // ---- Phase D: bias + LN2 + gelu + dense for BOTH tokens; dw rows loaded once ----
    {
        const int pos = t >> 2, sub = t & 3;
        const int co0 = sub * 10;
        float vv0[10], vv1[10];
        float s0 = 0.f, s1v = 0.f;
        #pragma unroll
        for (int u = 0; u < 10; u++) {
            float a = y2[pos * Y2S + co0 + u]         + p2s[co0 + u];
            float b = y2[Y2TOK + pos * Y2S + co0 + u] + p2s[co0 + u];
            vv0[u] = a; vv1[u] = b;
            s0 += a; s1v += b;
        }
        s0  += __shfl_xor(s0, 1, 64);  s1v += __shfl_xor(s1v, 1, 64);
        s0  += __shfl_xor(s0, 2, 64);  s1v += __shfl_xor(s1v, 2, 64);
        float mu0 = s0 * (1.0f / CH), mu1 = s1v * (1.0f / CH);
        float q0 = 0.f, q1 = 0.f;
        #pragma unroll
        for (int u = 0; u < 10; u++) {
            float d0 = vv0[u] - mu0; q0 += d0 * d0;
            float d1 = vv1[u] - mu1; q1 += d1 * d1;
        }
        q0 += __shfl_xor(q0, 1, 64);  q1 += __shfl_xor(q1, 1, 64);
        q0 += __shfl_xor(q0, 2, 64);  q1 += __shfl_xor(q1, 2, 64);
        float rs0 = rsqrtf(q0 * (1.0f / CH) + 1e-6f);
        float rs1 = rsqrtf(q1 * (1.0f / CH) + 1e-6f);

        float acc60[6] = {0,0,0,0,0,0}, acc61[6] = {0,0,0,0,0,0};
        const float* wp = &dw[(pos * CH + co0) * 6];
        #pragma unroll
        for (int u = 0; u < 10; u++) {
            float sc = p2s[40 + co0 + u], sb = p2s[80 + co0 + u];
            float gv0 = gelu_fast((vv0[u] - mu0) * rs0 * sc + sb);
            float gv1 = gelu_fast((vv1[u] - mu1) * rs1 * sc + sb);
            v2f w01 = *(const v2f*)&wp[u * 6];
            v2f w23 = *(const v2f*)&wp[u * 6 + 2];
            v2f w45 = *(const v2f*)&wp[u * 6 + 4];
            acc60[0] += gv0 * w01[0]; acc60[1] += gv0 * w01[1];
            acc60[2] += gv0 * w23[0]; acc60[3] += gv0 * w23[1];
            acc60[4] += gv0 * w45[0]; acc60[5] += gv0 * w45[1];
            acc61[0] += gv1 * w01[0]; acc61[1] += gv1 * w01[1];
            acc61[2] += gv1 * w23[0]; acc61[3] += gv1 * w23[1];
            acc61[4] += gv1 * w45[0]; acc61[5] += gv1 * w45[1];
        }
        #pragma unroll
        for (int off = 32; off > 0; off >>= 1)
            #pragma unroll
            for (int k = 0; k < 6; k++) {
                acc60[k] += __shfl_down(acc60[k], off, 64);
                acc61[k] += __shfl_down(acc61[k], off, 64);
            }
        int wv = t >> 6, lane = t & 63;
        if (lane == 0) {
            #pragma unroll
            for (int k = 0; k < 6; k++) {
                red[wv][0][k] = acc60[k];
                red[wv][1][k] = acc61[k];
            }
        }
        __syncthreads();
        if (t < 12) {
            int tk = t / 6, k = t - tk * 6;
            float s = red[0][tk][k] + red[1][tk][k] + red[2][tk][k] + red[3][tk][k] + db[k];
            out[fid[tk] * 6 + k] = s;
        }
    }
}

extern "C" void kernel_launch(void* const* d_in, const int* in_sizes, int n_in,
                              void* d_out, int out_size, void* d_ws, size_t ws_size,
                              hipStream_t stream) {
    const float* img = (const float*)d_in[0];
    // d_in[1] = masks: analytically redundant (mask == cell id), not read.
    const float* w1  = (const float*)d_in[2];
    const float* b1  = (const float*)d_in[3];
    const float* s1  = (const float*)d_in[4];
    const float* bb1 = (const float*)d_in[5];
    const float* w2  = (const float*)d_in[6];
    const float* b2  = (const float*)d_in[7];
    const float* s2  = (const float*)d_in[8];
    const float* bb2 = (const float*)d_in[9];
    const float* dw  = (const float*)d_in[10];
    const float* db  = (const float*)d_in[11];
    float* out = (float*)d_out;
    _Float16* ws = (_Float16*)d_ws;

    prep_kernel<<<32, 256, 0, stream>>>(w2, b1, s1, bb1, ws);
    sgn_kernel<<<2048, 256, 0, stream>>>(img, w1, b1, s1, bb1,
                                         b2, s2, bb2, dw, db, ws, out);
}